// Round 4
// baseline (437.803 us; speedup 1.0000x reference)
//
#include <hip/hip_runtime.h>

// GroupedEmbedding inverted: counting-sort ids by (table,row), then stream
// the weight tables once and multicast each row to its output positions.
// T=8 tables, E=100000 embeddings, D=128, N=200000 ids/table.
constexpr int T    = 8;
constexpr int E    = 100000;
constexpr int D    = 128;
constexpr int N    = 200000;
constexpr int ROWS = T * N;                 // 1,600,000 output rows
constexpr int NU   = T * E;                 // 800,000 (table,row) units
constexpr int EPB  = 4096;                  // scan elems/block (256 thr x 16)
constexpr int NBLK = (NU + EPB - 1) / EPB;  // 196

typedef float floatx4 __attribute__((ext_vector_type(4)));

// ---------- fallback: direct gather (round-3 kernel) ----------
__global__ __launch_bounds__(256) void grouped_embedding_gather(
    const int* __restrict__ vals,
    const float* __restrict__ weights,
    float* __restrict__ out) {
  const int lane       = threadIdx.x & 31;
  const int rowInBlock = threadIdx.x >> 5;
  const int rowsPerBlk = blockDim.x >> 5;
  const int rowStride  = gridDim.x * rowsPerBlk;
  for (int r = blockIdx.x * rowsPerBlk + rowInBlock; r < ROWS; r += rowStride) {
    const int id = __builtin_nontemporal_load(vals + r);
    const int t  = r / N;
    const floatx4* src = reinterpret_cast<const floatx4*>(
        weights + ((size_t)t * E + (size_t)id) * D);
    floatx4 v = src[lane];
    __builtin_nontemporal_store(
        v, reinterpret_cast<floatx4*>(out + (size_t)r * D) + lane);
  }
}

// ---------- counting-sort pipeline ----------
__global__ __launch_bounds__(256) void k_zero(unsigned* __restrict__ counts) {
  int i = blockIdx.x * blockDim.x + threadIdx.x;
  int stride = gridDim.x * blockDim.x;
  for (; i < NU; i += stride) counts[i] = 0u;
}

__global__ __launch_bounds__(256) void k_hist(const int* __restrict__ vals,
                                              unsigned* __restrict__ counts) {
  int r = blockIdx.x * blockDim.x + threadIdx.x;
  int stride = gridDim.x * blockDim.x;
  for (; r < ROWS; r += stride) {
    int id = __builtin_nontemporal_load(vals + r);
    atomicAdd(&counts[(r / N) * E + id], 1u);
  }
}

__global__ __launch_bounds__(256) void k_reduce(const unsigned* __restrict__ counts,
                                                unsigned* __restrict__ partials) {
  __shared__ unsigned s[256];
  const int base = blockIdx.x * EPB;
  unsigned sum = 0;
  for (int k = 0; k < 16; ++k) {
    int j = base + threadIdx.x + k * 256;
    if (j < NU) sum += counts[j];
  }
  s[threadIdx.x] = sum;
  __syncthreads();
  for (int off = 128; off > 0; off >>= 1) {
    if (threadIdx.x < off) s[threadIdx.x] += s[threadIdx.x + off];
    __syncthreads();
  }
  if (threadIdx.x == 0) partials[blockIdx.x] = s[0];
}

__global__ void k_scan_partials(unsigned* __restrict__ partials) {
  if (threadIdx.x == 0 && blockIdx.x == 0) {
    unsigned acc = 0;
    for (int i = 0; i < NBLK; ++i) {
      unsigned v = partials[i];
      partials[i] = acc;
      acc += v;
    }
  }
}

__global__ __launch_bounds__(256) void k_apply(const unsigned* __restrict__ counts,
                                               const unsigned* __restrict__ partials,
                                               unsigned* __restrict__ offsets,
                                               unsigned* __restrict__ cursors) {
  __shared__ unsigned s[256];
  const int base = blockIdx.x * EPB + threadIdx.x * 16;  // contiguous chunk
  unsigned loc[16];
  unsigned tot = 0;
  for (int k = 0; k < 16; ++k) {
    int j = base + k;
    unsigned c = (j < NU) ? counts[j] : 0u;
    loc[k] = tot;  // exclusive within this thread's chunk
    tot += c;
  }
  s[threadIdx.x] = tot;
  __syncthreads();
  for (int off = 1; off < 256; off <<= 1) {  // Hillis-Steele inclusive scan
    unsigned v = (threadIdx.x >= (unsigned)off) ? s[threadIdx.x - off] : 0u;
    __syncthreads();
    s[threadIdx.x] += v;
    __syncthreads();
  }
  const unsigned excl = s[threadIdx.x] - tot;  // exclusive across threads
  const unsigned blockBase = partials[blockIdx.x];
  for (int k = 0; k < 16; ++k) {
    int j = base + k;
    if (j < NU) {
      unsigned o = blockBase + excl + loc[k];
      offsets[j] = o;
      cursors[j] = o;
    }
  }
}

__global__ __launch_bounds__(256) void k_scatter(const int* __restrict__ vals,
                                                 unsigned* __restrict__ cursors,
                                                 unsigned* __restrict__ sorted_r) {
  int r = blockIdx.x * blockDim.x + threadIdx.x;
  int stride = gridDim.x * blockDim.x;
  for (; r < ROWS; r += stride) {
    int id = __builtin_nontemporal_load(vals + r);
    unsigned pos = atomicAdd(&cursors[(r / N) * E + id], 1u);
    sorted_r[pos] = (unsigned)r;
  }
}

// Stream weight rows sequentially; write each row to all its output slots.
// 32-lane group per unit, 16B/lane. Rows with count==0 are never fetched.
__global__ __launch_bounds__(256) void k_multicast(
    const float* __restrict__ weights,
    const unsigned* __restrict__ counts,
    const unsigned* __restrict__ offsets,
    const unsigned* __restrict__ sorted_r,
    float* __restrict__ out) {
  const int lane = threadIdx.x & 31;
  const int grp  = threadIdx.x >> 5;     // 0..7
  const int gpb  = blockDim.x >> 5;      // 8
  const int ustride = gridDim.x * gpb;
  for (int u = blockIdx.x * gpb + grp; u < NU; u += ustride) {
    const unsigned c = counts[u];
    if (c == 0) continue;
    const unsigned start = offsets[u];
    const floatx4 row =
        reinterpret_cast<const floatx4*>(weights + (size_t)u * D)[lane];
    for (unsigned k = 0; k < c; ++k) {
      const unsigned rr = sorted_r[start + k];
      __builtin_nontemporal_store(
          row, reinterpret_cast<floatx4*>(out + (size_t)rr * D) + lane);
    }
  }
}

extern "C" void kernel_launch(void* const* d_in, const int* in_sizes, int n_in,
                              void* d_out, int out_size, void* d_ws, size_t ws_size,
                              hipStream_t stream) {
  const int*   vals    = (const int*)d_in[0];
  const float* weights = (const float*)d_in[1];
  float*       out     = (float*)d_out;

  const size_t need = ((size_t)NU * 3 + 256 + (size_t)ROWS) * sizeof(unsigned);
  if (ws_size < need) {  // workspace too small: direct gather fallback
    grouped_embedding_gather<<<2048, 256, 0, stream>>>(vals, weights, out);
    return;
  }

  unsigned* counts   = (unsigned*)d_ws;      // [NU]
  unsigned* offsets  = counts + NU;          // [NU]
  unsigned* cursors  = offsets + NU;         // [NU]
  unsigned* partials = cursors + NU;         // [256 >= NBLK]
  unsigned* sorted_r = partials + 256;       // [ROWS]

  k_zero<<<1024, 256, 0, stream>>>(counts);
  k_hist<<<2048, 256, 0, stream>>>(vals, counts);
  k_reduce<<<NBLK, 256, 0, stream>>>(counts, partials);
  k_scan_partials<<<1, 64, 0, stream>>>(partials);
  k_apply<<<NBLK, 256, 0, stream>>>(counts, partials, offsets, cursors);
  k_scatter<<<2048, 256, 0, stream>>>(vals, cursors, sorted_r);
  k_multicast<<<2048, 256, 0, stream>>>(weights, counts, offsets, sorted_r, out);
}

// Round 5
// 251.388 us; speedup vs baseline: 1.7415x; 1.7415x over previous
//
#include <hip/hip_runtime.h>

// GroupedEmbedding: out[r, :] = weights[r / IDS, values[r], :]
// T=8 tables, E=100000 embeddings, D=128, N=200000 ids/table.
// Direct gather, batched: each 32-lane group handles 4 consecutive rows per
// iteration -> 1 vectorized id load, 4 back-to-back random row reads (4x
// memory-level parallelism for DRAM bank parallelism), and 4 NT stores
// forming one contiguous 2KB output chunk.
constexpr int T    = 8;
constexpr int E    = 100000;
constexpr int D    = 128;
constexpr int N    = 200000;
constexpr int ROWS = T * N;   // 1,600,000 (divisible by 32)

typedef float floatx4 __attribute__((ext_vector_type(4)));
typedef int   intx4   __attribute__((ext_vector_type(4)));

__global__ __launch_bounds__(256) void grouped_embedding_gather(
    const int* __restrict__ vals,
    const float* __restrict__ weights,
    float* __restrict__ out) {
  const int lane = threadIdx.x & 31;   // 16B slot within a row
  const int grp  = threadIdx.x >> 5;   // 0..7 (32-lane groups)
  // Each block covers 32 consecutive rows per iteration (8 groups x 4 rows).
  const int rowStride = gridDim.x * 32;

  for (int r0 = blockIdx.x * 32 + grp * 4; r0 < ROWS; r0 += rowStride) {
    // 4 consecutive ids, one 16B broadcast load. r0 % 4 == 0 and N % 4 == 0,
    // so all 4 rows belong to the same table.
    const intx4 ids =
        __builtin_nontemporal_load(reinterpret_cast<const intx4*>(vals + r0));
    const int t = r0 / N;  // magic-mul division
    const floatx4* __restrict__ w =
        reinterpret_cast<const floatx4*>(weights + (size_t)t * E * D);
    // 4 independent random 512B row reads in flight.
    const floatx4 v0 = w[(size_t)ids.x * 32 + lane];
    const floatx4 v1 = w[(size_t)ids.y * 32 + lane];
    const floatx4 v2 = w[(size_t)ids.z * 32 + lane];
    const floatx4 v3 = w[(size_t)ids.w * 32 + lane];
    // One contiguous 2KB NT-store chunk per group.
    floatx4* o = reinterpret_cast<floatx4*>(out + (size_t)r0 * D);
    __builtin_nontemporal_store(v0, o + lane);
    __builtin_nontemporal_store(v1, o + 32 + lane);
    __builtin_nontemporal_store(v2, o + 64 + lane);
    __builtin_nontemporal_store(v3, o + 96 + lane);
  }
}

extern "C" void kernel_launch(void* const* d_in, const int* in_sizes, int n_in,
                              void* d_out, int out_size, void* d_ws, size_t ws_size,
                              hipStream_t stream) {
  const int*   vals    = (const int*)d_in[0];
  const float* weights = (const float*)d_in[1];
  float*       out     = (float*)d_out;

  // 2048 blocks x 256 thr = 8 blocks/CU = 32 waves/CU (full occupancy).
  grouped_embedding_gather<<<2048, 256, 0, stream>>>(vals, weights, out);
}